// Round 2
// baseline (970.772 us; speedup 1.0000x reference)
//
#include <hip/hip_runtime.h>
#include <hip/hip_fp16.h>
#include <hip/hip_cooperative_groups.h>

#define NB 64
#define NS 512
#define NH 1024
#define NITERS 10
#define QC 128   // columns per persistent block

// -log(512)
#define LOG_INV_NS (-6.238324625039508f)

namespace cg = cooperative_groups;

using half8 = _Float16 __attribute__((ext_vector_type(8)));
using f32x4 = float __attribute__((ext_vector_type(4)));

// ---------------------------------------------------------------------------
// Kernel 1: row L2 norms for x and y. One wave per row (1024 floats).
__global__ __launch_bounds__(256) void norms_kernel(
    const float* __restrict__ x, const float* __restrict__ y,
    float* __restrict__ inv_nx, float* __restrict__ inv_ny) {
  int wid = threadIdx.x >> 6, lane = threadIdx.x & 63;
  int row = blockIdx.x * 4 + wid;  // 0..65535
  const float* base = (row < NB * NS) ? (x + (size_t)row * NH)
                                      : (y + (size_t)(row - NB * NS) * NH);
  const float4* p = (const float4*)base;
  float s = 0.f;
#pragma unroll
  for (int j = 0; j < 4; ++j) {
    float4 v = p[j * 64 + lane];
    s += v.x * v.x + v.y * v.y + v.z * v.z + v.w * v.w;
  }
#pragma unroll
  for (int o = 32; o; o >>= 1) s += __shfl_xor(s, o, 64);
  if (lane == 0) {
    float inv = 1.0f / fmaxf(sqrtf(s), 1e-12f);
    if (row < NB * NS) inv_nx[row] = inv;
    else inv_ny[row - NB * NS] = inv;
  }
}

// ---------------------------------------------------------------------------
// Kernel 2: batched GEMM  S[b][m][n] = sum_k xn[b][m][k] * yn[b][n][k]
// (unchanged from the verified round-1 kernel)
__global__ __launch_bounds__(256) void gemm_kernel(
    const float* __restrict__ x, const float* __restrict__ y,
    const float* __restrict__ inv_nx, const float* __restrict__ inv_ny,
    float* __restrict__ S) {
  __shared__ _Float16 As[128][40];
  __shared__ _Float16 Bs[128][40];

  int b = blockIdx.y;
  int tm = (blockIdx.x >> 2) * 128;
  int tn = (blockIdx.x & 3) * 128;
  int tid = threadIdx.x;
  int wid = tid >> 6, lane = tid & 63;
  int wr = (wid >> 1) * 64, wc = (wid & 1) * 64;
  int fr = lane & 15, fq = lane >> 4;

  int srow = tid >> 1;
  int skh = (tid & 1) * 16;
  const float* xb = x + ((size_t)b * NS + tm + srow) * NH + skh;
  const float* yb = y + ((size_t)b * NS + tn + srow) * NH + skh;
  float ax = inv_nx[b * NS + tm + srow];
  float ay = inv_ny[b * NS + tn + srow];

  f32x4 acc[4][4] = {};

  for (int k0 = 0; k0 < NH; k0 += 32) {
    __syncthreads();
    {
      const float4* px = (const float4*)(xb + k0);
      const float4* py = (const float4*)(yb + k0);
      alignas(16) _Float16 ta[16];
      alignas(16) _Float16 tb[16];
#pragma unroll
      for (int j = 0; j < 4; ++j) {
        float4 v = px[j];
        ta[4 * j + 0] = (_Float16)(v.x * ax);
        ta[4 * j + 1] = (_Float16)(v.y * ax);
        ta[4 * j + 2] = (_Float16)(v.z * ax);
        ta[4 * j + 3] = (_Float16)(v.w * ax);
      }
#pragma unroll
      for (int j = 0; j < 4; ++j) {
        float4 v = py[j];
        tb[4 * j + 0] = (_Float16)(v.x * ay);
        tb[4 * j + 1] = (_Float16)(v.y * ay);
        tb[4 * j + 2] = (_Float16)(v.z * ay);
        tb[4 * j + 3] = (_Float16)(v.w * ay);
      }
      *(half8*)&As[srow][skh + 0] = *(half8*)&ta[0];
      *(half8*)&As[srow][skh + 8] = *(half8*)&ta[8];
      *(half8*)&Bs[srow][skh + 0] = *(half8*)&tb[0];
      *(half8*)&Bs[srow][skh + 8] = *(half8*)&tb[8];
    }
    __syncthreads();

    half8 af[4], bf[4];
#pragma unroll
    for (int i = 0; i < 4; ++i) {
      af[i] = *(const half8*)&As[wr + 16 * i + fr][8 * fq];
      bf[i] = *(const half8*)&Bs[wc + 16 * i + fr][8 * fq];
    }
#pragma unroll
    for (int i = 0; i < 4; ++i)
#pragma unroll
      for (int j = 0; j < 4; ++j)
        acc[i][j] = __builtin_amdgcn_mfma_f32_16x16x32_f16(af[i], bf[j], acc[i][j], 0, 0, 0);
  }

#pragma unroll
  for (int i = 0; i < 4; ++i)
#pragma unroll
    for (int j = 0; j < 4; ++j) {
      size_t base = ((size_t)b * NS + tm + wr + 16 * i + 4 * fq) * NS + tn + wc + 16 * j + fr;
#pragma unroll
      for (int p = 0; p < 4; ++p) S[base + (size_t)p * NS] = acc[i][j][p];
    }
}

// ---------------------------------------------------------------------------
// Kernel 3: persistent cooperative Sinkhorn iterations.
// 256 blocks x 512 threads; block (b,q) owns cols [128q,128q+128) of batch b.
// S slice lives in LDS (f16, transposed [n][m]) for all 10 iterations.
__global__ __launch_bounds__(512) void sinkhorn_kernel(
    const float* __restrict__ S, float* __restrict__ partRow,
    float* __restrict__ outPart) {
  __shared__ _Float16 ShT[QC][NS];   // 128 KB, [local n][m]
  __shared__ float Ul[NS];           // 2 KB
  __shared__ float partR[8][NS];     // 16 KB, per-wave row partials
  __shared__ float Wl[QC];           // W for this block's cols
  __shared__ float Vl[QC];           // previous V for this block's cols
  __shared__ float outred[8];

  int blk = blockIdx.x;
  int b = blk >> 2, q = blk & 3;
  int t = threadIdx.x;
  int w = t >> 6, l = t & 63;

  // ---- stage S slice: fp32 [b][m][128q+n] -> f16 ShT[n][m] ----
  {
    const float* Sb = S + (size_t)b * NS * NS + q * QC;
    int mo = l & 15;                   // row offset within sweep
    int nch = (w * 4 + (l >> 4)) * 4;  // col chunk (4 floats)
#pragma unroll 4
    for (int s = 0; s < 32; ++s) {
      int m = 16 * s + mo;
      float4 v = *(const float4*)(Sb + (size_t)m * NS + nch);
      ShT[nch + 0][m] = (_Float16)v.x;
      ShT[nch + 1][m] = (_Float16)v.y;
      ShT[nch + 2][m] = (_Float16)v.z;
      ShT[nch + 3][m] = (_Float16)v.w;
    }
  }
  if (t < QC) { Wl[t] = LOG_INV_NS; Vl[t] = 0.f; }
  __syncthreads();

  cg::grid_group grid = cg::this_grid();
  float outacc = 0.f;

  for (int it = 1; it <= NITERS; ++it) {
    float f = 10.f * (float)it;
    int buf = it & 1;
    int last = (it == NITERS);

    // ---- row pass: racc[e] = sum over this block's 128 n of exp(f*S + W[n])
    // wave w handles n in [16w,16w+16); lane l owns rows m = 8l..8l+7.
    float racc[8] = {0.f, 0.f, 0.f, 0.f, 0.f, 0.f, 0.f, 0.f};
#pragma unroll 4
    for (int jn = 0; jn < 16; ++jn) {
      int n = 16 * w + jn;
      float wn = Wl[n];  // wave-uniform broadcast
      half8 hv = *(const half8*)&ShT[n][8 * l];
#pragma unroll
      for (int e = 0; e < 8; ++e)
        racc[e] += __expf(fmaf(f, (float)hv[e], wn));
    }
    {
      f32x4 r0 = {racc[0], racc[1], racc[2], racc[3]};
      f32x4 r1 = {racc[4], racc[5], racc[6], racc[7]};
      *(f32x4*)&partR[w][8 * l + 0] = r0;
      *(f32x4*)&partR[w][8 * l + 4] = r1;
    }
    __syncthreads();
    // combine the 8 wave partials; write this block's per-row partial to global
    {
      float r = 0.f;
#pragma unroll
      for (int k = 0; k < 8; ++k) r += partR[k][t];
      partRow[((size_t)(buf * NB + b) * 4 + q) * NS + t] = r;
    }
    __threadfence();
    grid.sync();

    // ---- U[m] from all 4 column-block partials ----
    {
      const float* pr = partRow + (size_t)(buf * NB + b) * 4 * NS;
      float s4 = pr[0 * NS + t] + pr[1 * NS + t] + pr[2 * NS + t] + pr[3 * NS + t];
      Ul[t] = LOG_INV_NS - __logf(s4);
    }
    __syncthreads();

    // ---- col pass: wave w owns n in [16w,16w+16), full m per read ----
    float um[8];
#pragma unroll
    for (int e = 0; e < 8; ++e) um[e] = Ul[8 * l + e];

    if (!last) {
#pragma unroll 4
      for (int jn = 0; jn < 16; ++jn) {
        int n = 16 * w + jn;
        half8 hv = *(const half8*)&ShT[n][8 * l];
        float c = 0.f;
#pragma unroll
        for (int e = 0; e < 8; ++e)
          c += __expf(fmaf(f, (float)hv[e], um[e]));
#pragma unroll
        for (int o = 32; o; o >>= 1) c += __shfl_xor(c, o, 64);
        if (l == 0) {
          float vnew = LOG_INV_NS - __logf(c);
          Wl[n] = 2.f * vnew - Vl[n];
          Vl[n] = vnew;
        }
      }
    } else {
      // last iteration: also accumulate D(n) = sum_m S*exp(...), emit d/c
#pragma unroll 2
      for (int jn = 0; jn < 16; ++jn) {
        int n = 16 * w + jn;
        half8 hv = *(const half8*)&ShT[n][8 * l];
        float c = 0.f, d = 0.f;
#pragma unroll
        for (int e = 0; e < 8; ++e) {
          float sv = (float)hv[e];
          float ev = __expf(fmaf(f, sv, um[e]));
          c += ev;
          d = fmaf(sv, ev, d);
        }
#pragma unroll
        for (int o = 32; o; o >>= 1) {
          c += __shfl_xor(c, o, 64);
          d += __shfl_xor(d, o, 64);
        }
        outacc += d / c;  // identical on all lanes
      }
    }
    __syncthreads();
  }

  if (l == 0) outred[w] = outacc;
  __syncthreads();
  if (t == 0) {
    float s = 0.f;
#pragma unroll
    for (int k = 0; k < 8; ++k) s += outred[k];
    outPart[b * 4 + q] = s * (1.0f / (float)NS);
  }
}

// ---------------------------------------------------------------------------
// Kernel 4: combine 4 partials per batch (deterministic)
__global__ void combine_kernel(const float* __restrict__ outPart, float* __restrict__ out) {
  int b = threadIdx.x;  // 64 threads
  out[b] = outPart[4 * b] + outPart[4 * b + 1] + outPart[4 * b + 2] + outPart[4 * b + 3];
}

// ---------------------------------------------------------------------------
extern "C" void kernel_launch(void* const* d_in, const int* in_sizes, int n_in,
                              void* d_out, int out_size, void* d_ws, size_t ws_size,
                              hipStream_t stream) {
  (void)in_sizes; (void)n_in; (void)out_size; (void)ws_size;
  const float* x = (const float*)d_in[0];
  const float* y = (const float*)d_in[1];
  float* out = (float*)d_out;

  float* S = (float*)d_ws;                           // 64*512*512 fp32
  float* inv_nx = S + (size_t)NB * NS * NS;          // 32768
  float* inv_ny = inv_nx + NB * NS;                  // 32768
  float* partRow = inv_ny + NB * NS;                 // 2*64*4*512
  float* outPart = partRow + (size_t)2 * NB * 4 * NS;  // 256

  norms_kernel<<<(NB * NS * 2) / 4, 256, 0, stream>>>(x, y, inv_nx, inv_ny);
  gemm_kernel<<<dim3(16, NB), 256, 0, stream>>>(x, y, inv_nx, inv_ny, S);

  void* args[] = {(void*)&S, (void*)&partRow, (void*)&outPart};
  hipLaunchCooperativeKernel(reinterpret_cast<void*>(sinkhorn_kernel),
                             dim3(NB * 4), dim3(512), args, 0, stream);

  combine_kernel<<<1, 64, 0, stream>>>(outPart, out);
}

// Round 3
// 270.852 us; speedup vs baseline: 3.5841x; 3.5841x over previous
//
#include <hip/hip_runtime.h>
#include <hip/hip_fp16.h>

#define NB 64
#define NS 512
#define NH 1024
#define NITERS 10

// -log(512)
#define LOG_INV_NS (-6.238324625039508f)

using half8 = _Float16 __attribute__((ext_vector_type(8)));
using half4 = _Float16 __attribute__((ext_vector_type(4)));
using f32x4 = float __attribute__((ext_vector_type(4)));

// ---------------------------------------------------------------------------
// Kernel 1: per-row L2 norm; F16 variant writes normalized f16 rows,
// fp32-fallback variant writes 1/norm only. One wave per row.
template <bool F16>
__global__ __launch_bounds__(256) void prep_kernel(
    const float* __restrict__ x, const float* __restrict__ y,
    _Float16* __restrict__ xh, _Float16* __restrict__ yh,
    float* __restrict__ inv_nx, float* __restrict__ inv_ny) {
  int wid = threadIdx.x >> 6, lane = threadIdx.x & 63;
  int row = blockIdx.x * 4 + wid;  // 0..65535
  bool isx = row < NB * NS;
  int lrow = isx ? row : row - NB * NS;
  const float* src = (isx ? x : y) + (size_t)lrow * NH;
  float4 v[4];
  float s = 0.f;
#pragma unroll
  for (int j = 0; j < 4; ++j) {
    v[j] = ((const float4*)src)[j * 64 + lane];
    s += v[j].x * v[j].x + v[j].y * v[j].y + v[j].z * v[j].z + v[j].w * v[j].w;
  }
#pragma unroll
  for (int o = 32; o; o >>= 1) s += __shfl_xor(s, o, 64);
  float inv = 1.0f / fmaxf(sqrtf(s), 1e-12f);
  if constexpr (F16) {
    _Float16* dst = (isx ? xh : yh) + (size_t)lrow * NH;
#pragma unroll
    for (int j = 0; j < 4; ++j) {
      half4 h = {(_Float16)(v[j].x * inv), (_Float16)(v[j].y * inv),
                 (_Float16)(v[j].z * inv), (_Float16)(v[j].w * inv)};
      ((half4*)dst)[j * 64 + lane] = h;
    }
  } else {
    if (lane == 0) {
      if (isx) inv_nx[lrow] = inv; else inv_ny[lrow] = inv;
    }
  }
}

// ---------------------------------------------------------------------------
// Kernel 2: batched GEMM S[b][m][n] = sum_k xn[b][m][k]*yn[b][n][k], f16 out.
// 128x128 tile, 4 waves (64x64 each), 16x16x32 f16 MFMA, BK=32.
// Grid decode pins batch%8 == blockIdx%8 (XCD L2 locality heuristic).
template <bool F16IN>
__global__ __launch_bounds__(256) void gemm_kernel(
    const float* __restrict__ x, const float* __restrict__ y,
    const float* __restrict__ inv_nx, const float* __restrict__ inv_ny,
    const _Float16* __restrict__ xh, const _Float16* __restrict__ yh,
    _Float16* __restrict__ Sh) {
  __shared__ _Float16 As[128][40];  // pad->80B stride: 2-way bank alias (free)
  __shared__ _Float16 Bs[128][40];

  int blk = blockIdx.x;
  int bs = blk & 7, rest = blk >> 3;
  int tile = rest & 15, bq = rest >> 4;
  int b = bq * 8 + bs;
  int tm = (tile >> 2) * 128, tn = (tile & 3) * 128;
  int tid = threadIdx.x;
  int wid = tid >> 6, lane = tid & 63;
  int wr = (wid >> 1) * 64, wc = (wid & 1) * 64;
  int fr = lane & 15, fq = lane >> 4;

  f32x4 acc[4][4] = {};

  // fp32-fallback staging params
  int srow = tid >> 1;
  int skh = (tid & 1) * 16;
  const float* xb32 = x + ((size_t)b * NS + tm + srow) * NH + skh;
  const float* yb32 = y + ((size_t)b * NS + tn + srow) * NH + skh;
  float ax = 0.f, ay = 0.f;
  if constexpr (!F16IN) {
    ax = inv_nx[b * NS + tm + srow];
    ay = inv_ny[b * NS + tn + srow];
  }

  // f16 staging params: chunk c = row*4 + kchunk; thread does c=tid, tid+256
  int r0 = tid >> 2, kc0 = (tid & 3) * 8;
  int r1 = 64 + (tid >> 2);
  const _Float16* xb16 = xh + ((size_t)b * NS + tm) * NH;
  const _Float16* yb16 = yh + ((size_t)b * NS + tn) * NH;

  for (int k0 = 0; k0 < NH; k0 += 32) {
    __syncthreads();
    if constexpr (F16IN) {
      *(half8*)&As[r0][kc0] = *(const half8*)(xb16 + (size_t)r0 * NH + k0 + kc0);
      *(half8*)&As[r1][kc0] = *(const half8*)(xb16 + (size_t)r1 * NH + k0 + kc0);
      *(half8*)&Bs[r0][kc0] = *(const half8*)(yb16 + (size_t)r0 * NH + k0 + kc0);
      *(half8*)&Bs[r1][kc0] = *(const half8*)(yb16 + (size_t)r1 * NH + k0 + kc0);
    } else {
      const float4* px = (const float4*)(xb32 + k0);
      const float4* py = (const float4*)(yb32 + k0);
      alignas(16) _Float16 ta[16];
      alignas(16) _Float16 tb[16];
#pragma unroll
      for (int j = 0; j < 4; ++j) {
        float4 v = px[j];
        ta[4 * j + 0] = (_Float16)(v.x * ax);
        ta[4 * j + 1] = (_Float16)(v.y * ax);
        ta[4 * j + 2] = (_Float16)(v.z * ax);
        ta[4 * j + 3] = (_Float16)(v.w * ax);
      }
#pragma unroll
      for (int j = 0; j < 4; ++j) {
        float4 v = py[j];
        tb[4 * j + 0] = (_Float16)(v.x * ay);
        tb[4 * j + 1] = (_Float16)(v.y * ay);
        tb[4 * j + 2] = (_Float16)(v.z * ay);
        tb[4 * j + 3] = (_Float16)(v.w * ay);
      }
      *(half8*)&As[srow][skh + 0] = *(half8*)&ta[0];
      *(half8*)&As[srow][skh + 8] = *(half8*)&ta[8];
      *(half8*)&Bs[srow][skh + 0] = *(half8*)&tb[0];
      *(half8*)&Bs[srow][skh + 8] = *(half8*)&tb[8];
    }
    __syncthreads();

    half8 af[4], bf[4];
#pragma unroll
    for (int i = 0; i < 4; ++i) {
      af[i] = *(const half8*)&As[wr + 16 * i + fr][8 * fq];
      bf[i] = *(const half8*)&Bs[wc + 16 * i + fr][8 * fq];
    }
#pragma unroll
    for (int i = 0; i < 4; ++i)
#pragma unroll
      for (int j = 0; j < 4; ++j)
        acc[i][j] = __builtin_amdgcn_mfma_f32_16x16x32_f16(af[i], bf[j], acc[i][j], 0, 0, 0);
  }

  // C/D layout: col = lane&15, row = (lane>>4)*4 + reg. f16 scalar stores.
  _Float16* Sb = Sh + (size_t)b * NS * NS;
#pragma unroll
  for (int i = 0; i < 4; ++i)
#pragma unroll
    for (int j = 0; j < 4; ++j) {
      int rr = tm + wr + 16 * i + 4 * fq;
      int cc = tn + wc + 16 * j + fr;
#pragma unroll
      for (int p = 0; p < 4; ++p)
        Sb[(size_t)(rr + p) * NS + cc] = (_Float16)acc[i][j][p];
    }
}

// ---------------------------------------------------------------------------
// Kernel 3: init V=0, W=log_nu
__global__ __launch_bounds__(256) void init_kernel(float* __restrict__ V, float* __restrict__ W) {
  int i = blockIdx.x * 256 + threadIdx.x;  // 32768
  V[i] = 0.f;
  W[i] = LOG_INV_NS;
}

// ---------------------------------------------------------------------------
// Kernel 4 (u/row step): U[b][m] = log_mu - log( sum_n exp(f*S[b][m][n] + W[b][n]) )
// 2048 blocks, 4 waves/block, 4 rows per wave, half8 loads.
__global__ __launch_bounds__(256) void u_kernel(
    const _Float16* __restrict__ Sh, const float* __restrict__ W,
    float* __restrict__ U, float f) {
  __shared__ float Wt[8][65];  // transposed W: Wt[e][l] = W[8l+e], pad for banks
  int blk = blockIdx.x;
  int bs = blk & 7, rest = blk >> 3;
  int rowgrp = rest & 31, bq = rest >> 5;
  int b = bq * 8 + bs;
  int t = threadIdx.x;
#pragma unroll
  for (int i = 0; i < 2; ++i) {
    int idx = t + 256 * i;
    Wt[idx & 7][idx >> 3] = W[b * NS + idx];
  }
  __syncthreads();
  int w = t >> 6, l = t & 63;
  float wn[8];
#pragma unroll
  for (int e = 0; e < 8; ++e) wn[e] = Wt[e][l];
  int m0 = rowgrp * 16 + w * 4;
  const _Float16* Sb = Sh + ((size_t)b * NS + m0) * NS + 8 * l;
  float sum[4] = {0.f, 0.f, 0.f, 0.f};
#pragma unroll
  for (int k = 0; k < 4; ++k) {
    half8 hv = *(const half8*)(Sb + (size_t)k * NS);
#pragma unroll
    for (int e = 0; e < 8; ++e) sum[k] += __expf(fmaf(f, (float)hv[e], wn[e]));
  }
#pragma unroll
  for (int o = 32; o; o >>= 1) {
#pragma unroll
    for (int k = 0; k < 4; ++k) sum[k] += __shfl_xor(sum[k], o, 64);
  }
  if (l == 0) {
#pragma unroll
    for (int k = 0; k < 4; ++k)
      U[b * NS + m0 + k] = LOG_INV_NS - __logf(sum[k]);
  }
}

// ---------------------------------------------------------------------------
// Kernel 5 (v/col step): per (b, col-quarter) block; coalesced row sweeps,
// per-thread 8-col partials, LDS combine. Last iter also emits
// sum_n (1/NS) * D(n)/C(n) partial for the output.
__global__ __launch_bounds__(256) void v_kernel(
    const _Float16* __restrict__ Sh, const float* __restrict__ U,
    float* __restrict__ V, float* __restrict__ W,
    float f, int last, float* __restrict__ outPart) {
  __shared__ float Ul[NS];
  __shared__ float partC[16][128];
  __shared__ float partD[16][128];
  __shared__ float red[128];
  int blk = blockIdx.x;
  int bs = blk & 7, rest = blk >> 3;
  int q = rest & 3, bq = rest >> 2;
  int b = bq * 8 + bs;
  int t = threadIdx.x;
  Ul[t] = U[b * NS + t];
  Ul[t + 256] = U[b * NS + t + 256];
  __syncthreads();

  int r = t >> 4, cg = t & 15;
  const _Float16* Sb = Sh + (size_t)b * NS * NS + q * 128 + cg * 8;
  float c[8] = {}, d[8] = {};
  if (!last) {
#pragma unroll 4
    for (int s = 0; s < 32; ++s) {
      int m = s * 16 + r;
      half8 hv = *(const half8*)(Sb + (size_t)m * NS);
      float um = Ul[m];
#pragma unroll
      for (int e = 0; e < 8; ++e) c[e] += __expf(fmaf(f, (float)hv[e], um));
    }
  } else {
#pragma unroll 2
    for (int s = 0; s < 32; ++s) {
      int m = s * 16 + r;
      half8 hv = *(const half8*)(Sb + (size_t)m * NS);
      float um = Ul[m];
#pragma unroll
      for (int e = 0; e < 8; ++e) {
        float sv = (float)hv[e];
        float ev = __expf(fmaf(f, sv, um));
        c[e] += ev;
        d[e] = fmaf(sv, ev, d[e]);
      }
    }
  }
  *(f32x4*)&partC[r][cg * 8 + 0] = f32x4{c[0], c[1], c[2], c[3]};
  *(f32x4*)&partC[r][cg * 8 + 4] = f32x4{c[4], c[5], c[6], c[7]};
  if (last) {
    *(f32x4*)&partD[r][cg * 8 + 0] = f32x4{d[0], d[1], d[2], d[3]};
    *(f32x4*)&partD[r][cg * 8 + 4] = f32x4{d[4], d[5], d[6], d[7]};
  }
  __syncthreads();
  if (t < 128) {
    float ct = 0.f;
#pragma unroll
    for (int r2 = 0; r2 < 16; ++r2) ct += partC[r2][t];
    float vnew = LOG_INV_NS - __logf(ct);
    int n = b * NS + q * 128 + t;
    float vold = V[n];
    V[n] = vnew;
    W[n] = 2.f * vnew - vold;
    if (last) {
      float dt = 0.f;
#pragma unroll
      for (int r2 = 0; r2 < 16; ++r2) dt += partD[r2][t];
      red[t] = dt / ct;
    }
  }
  if (last) {
    __syncthreads();
    for (int s2 = 64; s2 > 0; s2 >>= 1) {
      if (t < s2) red[t] += red[t + s2];
      __syncthreads();
    }
    if (t == 0) outPart[b * 4 + q] = red[0] * (1.0f / (float)NS);
  }
}

// ---------------------------------------------------------------------------
// Kernel 6: combine 4 partials per batch (deterministic)
__global__ void combine_kernel(const float* __restrict__ outPart, float* __restrict__ out) {
  int b = threadIdx.x;  // 64 threads
  out[b] = outPart[4 * b] + outPart[4 * b + 1] + outPart[4 * b + 2] + outPart[4 * b + 3];
}

// ---------------------------------------------------------------------------
extern "C" void kernel_launch(void* const* d_in, const int* in_sizes, int n_in,
                              void* d_out, int out_size, void* d_ws, size_t ws_size,
                              hipStream_t stream) {
  (void)in_sizes; (void)n_in; (void)out_size;
  const float* x = (const float*)d_in[0];
  const float* y = (const float*)d_in[1];
  float* out = (float*)d_out;

  char* ws = (char*)d_ws;
  _Float16* Sh = (_Float16*)ws;                                // 32 MiB
  float* fregion = (float*)(ws + (size_t)NB * NS * NS * 2);
  float* inv_nx = fregion;                                     // 32768
  float* inv_ny = inv_nx + NB * NS;
  float* U = inv_ny + NB * NS;
  float* V = U + NB * NS;
  float* W = V + NB * NS;
  float* outPart = W + NB * NS;                                // 256
  size_t base = (size_t)NB * NS * NS * 2 + (5 * NB * NS + 256) * 4;  // 34,210,816
  _Float16* xh = (_Float16*)(ws + base);
  _Float16* yh = xh + (size_t)NB * NS * NH;
  size_t need = base + (size_t)2 * NB * NS * NH * 2;           // ~160.6 MiB
  bool f16in = ws_size >= need;

  if (f16in) {
    prep_kernel<true><<<(2 * NB * NS) / 4, 256, 0, stream>>>(x, y, xh, yh, inv_nx, inv_ny);
    gemm_kernel<true><<<1024, 256, 0, stream>>>(x, y, inv_nx, inv_ny, xh, yh, Sh);
  } else {
    prep_kernel<false><<<(2 * NB * NS) / 4, 256, 0, stream>>>(x, y, xh, yh, inv_nx, inv_ny);
    gemm_kernel<false><<<1024, 256, 0, stream>>>(x, y, inv_nx, inv_ny, xh, yh, Sh);
  }
  init_kernel<<<(NB * NS) / 256, 256, 0, stream>>>(V, W);

  for (int t = 1; t <= NITERS; ++t) {
    float f = 10.0f * (float)t;
    u_kernel<<<2048, 256, 0, stream>>>(Sh, W, U, f);
    v_kernel<<<256, 256, 0, stream>>>(Sh, U, V, W, f, t == NITERS ? 1 : 0, outPart);
  }
  combine_kernel<<<1, 64, 0, stream>>>(outPart, out);
}

// Round 5
// 257.385 us; speedup vs baseline: 3.7717x; 1.0523x over previous
//
#include <hip/hip_runtime.h>
#include <hip/hip_fp16.h>

#define NB 64
#define NS 512
#define NH 1024
#define NITERS 10

// -log(512)
#define LOG_INV_NS (-6.238324625039508f)

using half8 = _Float16 __attribute__((ext_vector_type(8)));
using half4 = _Float16 __attribute__((ext_vector_type(4)));
using f32x4 = float __attribute__((ext_vector_type(4)));

// ---------------------------------------------------------------------------
// Kernel 1: per-row L2 norm + normalized f16 row output.
// 2 rows per wave (ILP: two independent shuffle-reduce chains).
__global__ __launch_bounds__(256) void prep_kernel(
    const float* __restrict__ x, const float* __restrict__ y,
    _Float16* __restrict__ xh, _Float16* __restrict__ yh) {
  int wid = threadIdx.x >> 6, lane = threadIdx.x & 63;
  int row0 = blockIdx.x * 8 + wid * 2;  // even; pair never straddles x/y
  bool isx = row0 < NB * NS;
  int lrow = isx ? row0 : row0 - NB * NS;
  const float* src = (isx ? x : y) + (size_t)lrow * NH;
  _Float16* dst = (isx ? xh : yh) + (size_t)lrow * NH;

  float4 v0[4], v1[4];
  float s0 = 0.f, s1 = 0.f;
#pragma unroll
  for (int j = 0; j < 4; ++j) {
    v0[j] = ((const float4*)src)[j * 64 + lane];
    v1[j] = ((const float4*)src)[256 + j * 64 + lane];
  }
#pragma unroll
  for (int j = 0; j < 4; ++j) {
    s0 += v0[j].x * v0[j].x + v0[j].y * v0[j].y + v0[j].z * v0[j].z + v0[j].w * v0[j].w;
    s1 += v1[j].x * v1[j].x + v1[j].y * v1[j].y + v1[j].z * v1[j].z + v1[j].w * v1[j].w;
  }
#pragma unroll
  for (int o = 32; o; o >>= 1) {
    s0 += __shfl_xor(s0, o, 64);
    s1 += __shfl_xor(s1, o, 64);
  }
  float i0 = 1.0f / fmaxf(sqrtf(s0), 1e-12f);
  float i1 = 1.0f / fmaxf(sqrtf(s1), 1e-12f);
#pragma unroll
  for (int j = 0; j < 4; ++j) {
    half4 h0 = {(_Float16)(v0[j].x * i0), (_Float16)(v0[j].y * i0),
                (_Float16)(v0[j].z * i0), (_Float16)(v0[j].w * i0)};
    half4 h1 = {(_Float16)(v1[j].x * i1), (_Float16)(v1[j].y * i1),
                (_Float16)(v1[j].z * i1), (_Float16)(v1[j].w * i1)};
    ((half4*)dst)[j * 64 + lane] = h0;
    ((half4*)(dst + NH))[j * 64 + lane] = h1;
  }
}

// fp32-fallback: norms only (used with the fallback GEMM when ws is small)
__global__ __launch_bounds__(256) void norms_kernel(
    const float* __restrict__ x, const float* __restrict__ y,
    float* __restrict__ inv_nx, float* __restrict__ inv_ny) {
  int wid = threadIdx.x >> 6, lane = threadIdx.x & 63;
  int row = blockIdx.x * 4 + wid;
  bool isx = row < NB * NS;
  int lrow = isx ? row : row - NB * NS;
  const float* src = (isx ? x : y) + (size_t)lrow * NH;
  float s = 0.f;
#pragma unroll
  for (int j = 0; j < 4; ++j) {
    float4 v = ((const float4*)src)[j * 64 + lane];
    s += v.x * v.x + v.y * v.y + v.z * v.z + v.w * v.w;
  }
#pragma unroll
  for (int o = 32; o; o >>= 1) s += __shfl_xor(s, o, 64);
  if (lane == 0) {
    float inv = 1.0f / fmaxf(sqrtf(s), 1e-12f);
    if (isx) inv_nx[lrow] = inv; else inv_ny[lrow] = inv;
  }
}

// ---------------------------------------------------------------------------
// Kernel 2 (f16 path): batched GEMM S[b][m][n] = sum_k xh[b][m][k]*yh[b][n][k]
// 128x128 tile, 4 waves (64x64 each), 16x16x32 f16 MFMA, BK=64,
// 2-phase register prefetch (FULL tile coverage: 2 half8 per row per matrix),
// LDS-transpose epilogue for coalesced f16 stores.
__global__ __launch_bounds__(256) void gemm_f16(
    const _Float16* __restrict__ xh, const _Float16* __restrict__ yh,
    _Float16* __restrict__ Sh) {
  __shared__ __align__(16) char smem[2][128 * 72 * 2];
  _Float16(*As)[72] = (_Float16(*)[72])smem[0];
  _Float16(*Bs)[72] = (_Float16(*)[72])smem[1];

  int blk = blockIdx.x;
  int bs = blk & 7, rest = blk >> 3;
  int tile = rest & 15, bq = rest >> 4;
  int b = bq * 8 + bs;
  int tm = (tile >> 2) * 128, tn = (tile & 3) * 128;
  int tid = threadIdx.x;
  int wid = tid >> 6, lane = tid & 63;
  int wr = (wid >> 1) * 64, wc = (wid & 1) * 64;
  int fr = lane & 15, fq = lane >> 4;

  // staging: rows r0=tid>>2 and r1=64+r0, col chunk kc=(tid&3)*16 (16 halves).
  int r0 = tid >> 2, kc = (tid & 3) * 16;
  int r1 = 64 + r0;
  const _Float16* xb = xh + ((size_t)b * NS + tm) * NH + kc;
  const _Float16* yb = yh + ((size_t)b * NS + tn) * NH + kc;

  f32x4 acc[4][4] = {};
  half8 ra[4], rb[4];

#define GLOAD(K0)                                                  \
  do {                                                             \
    ra[0] = *(const half8*)(xb + (size_t)r0 * NH + (K0) + 0);      \
    ra[1] = *(const half8*)(xb + (size_t)r0 * NH + (K0) + 8);      \
    ra[2] = *(const half8*)(xb + (size_t)r1 * NH + (K0) + 0);      \
    ra[3] = *(const half8*)(xb + (size_t)r1 * NH + (K0) + 8);      \
    rb[0] = *(const half8*)(yb + (size_t)r0 * NH + (K0) + 0);      \
    rb[1] = *(const half8*)(yb + (size_t)r0 * NH + (K0) + 8);      \
    rb[2] = *(const half8*)(yb + (size_t)r1 * NH + (K0) + 0);      \
    rb[3] = *(const half8*)(yb + (size_t)r1 * NH + (K0) + 8);      \
  } while (0)

  GLOAD(0);

  for (int k0 = 0; k0 < NH; k0 += 64) {
    __syncthreads();
    *(half8*)&As[r0][kc + 0] = ra[0];
    *(half8*)&As[r0][kc + 8] = ra[1];
    *(half8*)&As[r1][kc + 0] = ra[2];
    *(half8*)&As[r1][kc + 8] = ra[3];
    *(half8*)&Bs[r0][kc + 0] = rb[0];
    *(half8*)&Bs[r0][kc + 8] = rb[1];
    *(half8*)&Bs[r1][kc + 0] = rb[2];
    *(half8*)&Bs[r1][kc + 8] = rb[3];
    __syncthreads();
    if (k0 + 64 < NH) GLOAD(k0 + 64);
#pragma unroll
    for (int ks = 0; ks < 2; ++ks) {
      half8 af[4], bf[4];
#pragma unroll
      for (int i = 0; i < 4; ++i) {
        af[i] = *(const half8*)&As[wr + 16 * i + fr][ks * 32 + 8 * fq];
        bf[i] = *(const half8*)&Bs[wc + 16 * i + fr][ks * 32 + 8 * fq];
      }
#pragma unroll
      for (int i = 0; i < 4; ++i)
#pragma unroll
        for (int j = 0; j < 4; ++j)
          acc[i][j] = __builtin_amdgcn_mfma_f32_16x16x32_f16(af[i], bf[j], acc[i][j], 0, 0, 0);
    }
  }
#undef GLOAD

  // Epilogue: stage C tile f16 in LDS (overlays As/Bs), coalesced stores.
  // C/D layout: col = lane&15 (n), row = (lane>>4)*4 + reg (m).
  _Float16(*Cs)[132] = (_Float16(*)[132])smem[0];
  __syncthreads();
#pragma unroll
  for (int i = 0; i < 4; ++i)
#pragma unroll
    for (int j = 0; j < 4; ++j) {
      int rr = wr + 16 * i + 4 * fq;
      int cc = wc + 16 * j + fr;
#pragma unroll
      for (int p = 0; p < 4; ++p) Cs[rr + p][cc] = (_Float16)acc[i][j][p];
    }
  __syncthreads();
  {
    _Float16* Sb = Sh + (size_t)b * NS * NS;
    int row = tid >> 1, h0 = (tid & 1) * 64;
    _Float16* gout = Sb + (size_t)(tm + row) * NS + tn + h0;
#pragma unroll
    for (int c = 0; c < 8; ++c)
      *(half8*)(gout + c * 8) = *(const half8*)&Cs[row][h0 + c * 8];
  }
}

// ---------------------------------------------------------------------------
// Kernel 2b (fallback, fp32 inputs): round-3 verbatim structure, BK=32.
__global__ __launch_bounds__(256) void gemm_f32(
    const float* __restrict__ x, const float* __restrict__ y,
    const float* __restrict__ inv_nx, const float* __restrict__ inv_ny,
    _Float16* __restrict__ Sh) {
  __shared__ _Float16 As[128][40];
  __shared__ _Float16 Bs[128][40];

  int blk = blockIdx.x;
  int bs = blk & 7, rest = blk >> 3;
  int tile = rest & 15, bq = rest >> 4;
  int b = bq * 8 + bs;
  int tm = (tile >> 2) * 128, tn = (tile & 3) * 128;
  int tid = threadIdx.x;
  int wid = tid >> 6, lane = tid & 63;
  int wr = (wid >> 1) * 64, wc = (wid & 1) * 64;
  int fr = lane & 15, fq = lane >> 4;

  int srow = tid >> 1;
  int skh = (tid & 1) * 16;
  const float* xb32 = x + ((size_t)b * NS + tm + srow) * NH + skh;
  const float* yb32 = y + ((size_t)b * NS + tn + srow) * NH + skh;
  float ax = inv_nx[b * NS + tm + srow];
  float ay = inv_ny[b * NS + tn + srow];

  f32x4 acc[4][4] = {};

  for (int k0 = 0; k0 < NH; k0 += 32) {
    __syncthreads();
    {
      const float4* px = (const float4*)(xb32 + k0);
      const float4* py = (const float4*)(yb32 + k0);
      alignas(16) _Float16 ta[16];
      alignas(16) _Float16 tb[16];
#pragma unroll
      for (int j = 0; j < 4; ++j) {
        float4 v = px[j];
        ta[4 * j + 0] = (_Float16)(v.x * ax);
        ta[4 * j + 1] = (_Float16)(v.y * ax);
        ta[4 * j + 2] = (_Float16)(v.z * ax);
        ta[4 * j + 3] = (_Float16)(v.w * ax);
      }
#pragma unroll
      for (int j = 0; j < 4; ++j) {
        float4 v = py[j];
        tb[4 * j + 0] = (_Float16)(v.x * ay);
        tb[4 * j + 1] = (_Float16)(v.y * ay);
        tb[4 * j + 2] = (_Float16)(v.z * ay);
        tb[4 * j + 3] = (_Float16)(v.w * ay);
      }
      *(half8*)&As[srow][skh + 0] = *(half8*)&ta[0];
      *(half8*)&As[srow][skh + 8] = *(half8*)&ta[8];
      *(half8*)&Bs[srow][skh + 0] = *(half8*)&tb[0];
      *(half8*)&Bs[srow][skh + 8] = *(half8*)&tb[8];
    }
    __syncthreads();

    half8 af[4], bf[4];
#pragma unroll
    for (int i = 0; i < 4; ++i) {
      af[i] = *(const half8*)&As[wr + 16 * i + fr][8 * fq];
      bf[i] = *(const half8*)&Bs[wc + 16 * i + fr][8 * fq];
    }
#pragma unroll
    for (int i = 0; i < 4; ++i)
#pragma unroll
      for (int j = 0; j < 4; ++j)
        acc[i][j] = __builtin_amdgcn_mfma_f32_16x16x32_f16(af[i], bf[j], acc[i][j], 0, 0, 0);
  }

  _Float16* Sb = Sh + (size_t)b * NS * NS;
#pragma unroll
  for (int i = 0; i < 4; ++i)
#pragma unroll
    for (int j = 0; j < 4; ++j) {
      int rr = tm + wr + 16 * i + 4 * fq;
      int cc = tn + wc + 16 * j + fr;
#pragma unroll
      for (int p = 0; p < 4; ++p)
        Sb[(size_t)(rr + p) * NS + cc] = (_Float16)acc[i][j][p];
    }
}

// ---------------------------------------------------------------------------
// Kernel 3: init V=0, W=log_nu
__global__ __launch_bounds__(256) void init_kernel(float* __restrict__ V, float* __restrict__ W) {
  int i = blockIdx.x * 256 + threadIdx.x;  // 32768
  V[i] = 0.f;
  W[i] = LOG_INV_NS;
}

// ---------------------------------------------------------------------------
// Kernel 4 (u/row step): U[b][m] = log_mu - log( sum_n exp(f*S[b][m][n] + W[b][n]) )
__global__ __launch_bounds__(256) void u_kernel(
    const _Float16* __restrict__ Sh, const float* __restrict__ W,
    float* __restrict__ U, float f) {
  __shared__ float Wt[8][65];
  int blk = blockIdx.x;
  int bs = blk & 7, rest = blk >> 3;
  int rowgrp = rest & 31, bq = rest >> 5;
  int b = bq * 8 + bs;
  int t = threadIdx.x;
#pragma unroll
  for (int i = 0; i < 2; ++i) {
    int idx = t + 256 * i;
    Wt[idx & 7][idx >> 3] = W[b * NS + idx];
  }
  __syncthreads();
  int w = t >> 6, l = t & 63;
  float wn[8];
#pragma unroll
  for (int e = 0; e < 8; ++e) wn[e] = Wt[e][l];
  int m0 = rowgrp * 16 + w * 4;
  const _Float16* Sb = Sh + ((size_t)b * NS + m0) * NS + 8 * l;
  float sum[4] = {0.f, 0.f, 0.f, 0.f};
#pragma unroll
  for (int k = 0; k < 4; ++k) {
    half8 hv = *(const half8*)(Sb + (size_t)k * NS);
#pragma unroll
    for (int e = 0; e < 8; ++e) sum[k] += __expf(fmaf(f, (float)hv[e], wn[e]));
  }
#pragma unroll
  for (int o = 32; o; o >>= 1) {
#pragma unroll
    for (int k = 0; k < 4; ++k) sum[k] += __shfl_xor(sum[k], o, 64);
  }
  if (l == 0) {
#pragma unroll
    for (int k = 0; k < 4; ++k)
      U[b * NS + m0 + k] = LOG_INV_NS - __logf(sum[k]);
  }
}

// ---------------------------------------------------------------------------
// Kernel 5 (v/col step)
__global__ __launch_bounds__(256) void v_kernel(
    const _Float16* __restrict__ Sh, const float* __restrict__ U,
    float* __restrict__ V, float* __restrict__ W,
    float f, int last, float* __restrict__ outPart) {
  __shared__ float Ul[NS];
  __shared__ float partC[16][128];
  __shared__ float partD[16][128];
  __shared__ float red[128];
  int blk = blockIdx.x;
  int bs = blk & 7, rest = blk >> 3;
  int q = rest & 3, bq = rest >> 2;
  int b = bq * 8 + bs;
  int t = threadIdx.x;
  Ul[t] = U[b * NS + t];
  Ul[t + 256] = U[b * NS + t + 256];
  __syncthreads();

  int r = t >> 4, cg = t & 15;
  const _Float16* Sb = Sh + (size_t)b * NS * NS + q * 128 + cg * 8;
  float c[8] = {}, d[8] = {};
  if (!last) {
#pragma unroll 4
    for (int s = 0; s < 32; ++s) {
      int m = s * 16 + r;
      half8 hv = *(const half8*)(Sb + (size_t)m * NS);
      float um = Ul[m];
#pragma unroll
      for (int e = 0; e < 8; ++e) c[e] += __expf(fmaf(f, (float)hv[e], um));
    }
  } else {
#pragma unroll 2
    for (int s = 0; s < 32; ++s) {
      int m = s * 16 + r;
      half8 hv = *(const half8*)(Sb + (size_t)m * NS);
      float um = Ul[m];
#pragma unroll
      for (int e = 0; e < 8; ++e) {
        float sv = (float)hv[e];
        float ev = __expf(fmaf(f, sv, um));
        c[e] += ev;
        d[e] = fmaf(sv, ev, d[e]);
      }
    }
  }
  *(f32x4*)&partC[r][cg * 8 + 0] = f32x4{c[0], c[1], c[2], c[3]};
  *(f32x4*)&partC[r][cg * 8 + 4] = f32x4{c[4], c[5], c[6], c[7]};
  if (last) {
    *(f32x4*)&partD[r][cg * 8 + 0] = f32x4{d[0], d[1], d[2], d[3]};
    *(f32x4*)&partD[r][cg * 8 + 4] = f32x4{d[4], d[5], d[6], d[7]};
  }
  __syncthreads();
  if (t < 128) {
    float ct = 0.f;
#pragma unroll
    for (int r2 = 0; r2 < 16; ++r2) ct += partC[r2][t];
    float vnew = LOG_INV_NS - __logf(ct);
    int n = b * NS + q * 128 + t;
    float vold = V[n];
    V[n] = vnew;
    W[n] = 2.f * vnew - vold;
    if (last) {
      float dt = 0.f;
#pragma unroll
      for (int r2 = 0; r2 < 16; ++r2) dt += partD[r2][t];
      red[t] = dt / ct;
    }
  }
  if (last) {
    __syncthreads();
    for (int s2 = 64; s2 > 0; s2 >>= 1) {
      if (t < s2) red[t] += red[t + s2];
      __syncthreads();
    }
    if (t == 0) outPart[b * 4 + q] = red[0] * (1.0f / (float)NS);
  }
}

// ---------------------------------------------------------------------------
// Kernel 6: combine 4 partials per batch (deterministic)
__global__ void combine_kernel(const float* __restrict__ outPart, float* __restrict__ out) {
  int b = threadIdx.x;  // 64 threads
  out[b] = outPart[4 * b] + outPart[4 * b + 1] + outPart[4 * b + 2] + outPart[4 * b + 3];
}

// ---------------------------------------------------------------------------
extern "C" void kernel_launch(void* const* d_in, const int* in_sizes, int n_in,
                              void* d_out, int out_size, void* d_ws, size_t ws_size,
                              hipStream_t stream) {
  (void)in_sizes; (void)n_in; (void)out_size;
  const float* x = (const float*)d_in[0];
  const float* y = (const float*)d_in[1];
  float* out = (float*)d_out;

  char* ws = (char*)d_ws;
  _Float16* Sh = (_Float16*)ws;                                // 32 MiB
  float* fregion = (float*)(ws + (size_t)NB * NS * NS * 2);
  float* inv_nx = fregion;                                     // 32768
  float* inv_ny = inv_nx + NB * NS;
  float* U = inv_ny + NB * NS;
  float* V = U + NB * NS;
  float* W = V + NB * NS;
  float* outPart = W + NB * NS;                                // 256
  size_t base = (size_t)NB * NS * NS * 2 + (5 * NB * NS + 256) * 4;
  _Float16* xh = (_Float16*)(ws + base);
  _Float16* yh = xh + (size_t)NB * NS * NH;
  size_t need = base + (size_t)2 * NB * NS * NH * 2;           // ~160.6 MiB
  bool f16in = ws_size >= need;

  if (f16in) {
    prep_kernel<<<(2 * NB * NS) / 8, 256, 0, stream>>>(x, y, xh, yh);
    gemm_f16<<<1024, 256, 0, stream>>>(xh, yh, Sh);
  } else {
    norms_kernel<<<(2 * NB * NS) / 4, 256, 0, stream>>>(x, y, inv_nx, inv_ny);
    gemm_f32<<<1024, 256, 0, stream>>>(x, y, inv_nx, inv_ny, Sh);
  }
  init_kernel<<<(NB * NS) / 256, 256, 0, stream>>>(V, W);

  for (int t = 1; t <= NITERS; ++t) {
    float f = 10.0f * (float)t;
    u_kernel<<<2048, 256, 0, stream>>>(Sh, W, U, f);
    v_kernel<<<256, 256, 0, stream>>>(Sh, U, V, W, f, t == NITERS ? 1 : 0, outPart);
  }
  combine_kernel<<<1, 64, 0, stream>>>(outPart, out);
}